// Round 1
// baseline (329.841 us; speedup 1.0000x reference)
//
#include <hip/hip_runtime.h>
#include <stdint.h>

// Decomposition (unchanged):
//   UV[n][j] = z[n] . Wcat[:,j] (+ b1[j] for j<128), stored bf16, j in 0..255
//     where Wcat[k][j] = (j<128) ? W1[j][k] : W1[j-128][64+k]
//   out[e] = b2 + sum_j W2[j] * relu(UV[row[e]][j] + UV[col[e]][128+j])
//
// R3 change (node kernel only; edge kernel byte-identical to R2):
//   The node precompute was latency-serialized: 512 blocks = 2 blocks/CU (25%
//   occupancy) and each grid-stride iteration was load -> barrier -> compute ->
//   barrier, exposing full HBM latency 13 times with nothing to overlap it.
//   Now: grid 2048 (8 blocks/CU), LDS double-buffer + register prefetch of the
//   next z tile issued before the MFMAs, ONE barrier per iteration. The vmcnt
//   wait for the prefetch lands at the next iteration's ds_write, so load
//   latency hides under compute. Target: ~108 us -> ~20 us.

typedef __attribute__((ext_vector_type(8))) short bf16x8;
typedef __attribute__((ext_vector_type(4))) float f32x4;

__device__ inline unsigned short f2bf(float f) {
    uint32_t u = __builtin_bit_cast(uint32_t, f);
    uint32_t r = (u + 0x7FFFu + ((u >> 16) & 1u)) >> 16;  // RNE
    return (unsigned short)r;
}

// ---------------- Kernel 1: node precompute via MFMA --------------------------
// Block = 256 threads = 4 waves. Wave w owns output cols [w*64, w*64+64) as
// 4 N-tiles of 16. B-fragments (weights, bf16) loaded ONCE into registers:
//   B[k][n] with n = w*64 + nt*16 + (lane&15), k = kh*32 + (lane>>4)*8 + j.
// Per iteration: one 16-node z tile in LDS (double-buffered, padded rows),
// A-frags via ds_read_b128, 8 MFMAs/wave, scalar bf16 epilogue stores.
__global__ __launch_bounds__(256) void node_precompute_mfma(
    const float* __restrict__ z, const float* __restrict__ W1,
    const float* __restrict__ b1, unsigned short* __restrict__ UV,
    int n_nodes)
{
    __shared__ __align__(16) unsigned short zs[2][16][72];  // 72 = 64 + 8 pad

    const int tid = threadIdx.x;
    const int w  = tid >> 6;    // wave 0..3
    const int l  = tid & 63;
    const int lm = l & 15;      // A-row / B-col / C-col sublane
    const int q  = l >> 4;      // quad 0..3

    // ---- one-time: weight B-fragments + per-col bias into registers ----
    bf16x8 bfrag[4][2];
    float  bias[4];
#pragma unroll
    for (int nt = 0; nt < 4; ++nt) {
        const int n = w * 64 + nt * 16 + lm;               // output col 0..255
        const float* wrow = (n < 128) ? (W1 + (size_t)n * 128)
                                      : (W1 + (size_t)(n - 128) * 128 + 64);
#pragma unroll
        for (int kh = 0; kh < 2; ++kh) {
            const int k0 = kh * 32 + q * 8;
            bf16x8 bb;
#pragma unroll
            for (int j = 0; j < 8; ++j) bb[j] = (short)f2bf(wrow[k0 + j]);
            bfrag[nt][kh] = bb;
        }
        bias[nt] = (n < 128) ? b1[n] : 0.f;
    }

    const int ntiles = (n_nodes + 15) >> 4;
    const int iters = (ntiles + gridDim.x - 1) / gridDim.x;  // uniform for barriers
    int tile = blockIdx.x;

    const int srow = tid >> 4;        // staging: thread -> (row, 4-float chunk)
    const int scol = (tid & 15) * 4;

    // prefetch first tile into registers
    float4 zv = make_float4(0.f, 0.f, 0.f, 0.f);
    if (tile < ntiles && tile * 16 + srow < n_nodes)
        zv = *(const float4*)(z + (size_t)(tile * 16 + srow) * 64 + scol);

    for (int it = 0; it < iters; ++it) {
        const int buf = it & 1;
        const int node0 = tile * 16;

        if (tile < ntiles) {
            unsigned short* p = &zs[buf][srow][scol];   // waits vmcnt for zv
            p[0] = f2bf(zv.x); p[1] = f2bf(zv.y); p[2] = f2bf(zv.z); p[3] = f2bf(zv.w);
        }
        __syncthreads();   // buf is fully staged; (also releases buf^1 for next iter)

        // issue next tile's global load BEFORE compute — latency hides under
        // the MFMAs/stores; the wait lands at next iteration's ds_write.
        const int ntile = tile + gridDim.x;
        float4 zn = make_float4(0.f, 0.f, 0.f, 0.f);
        if (it + 1 < iters && ntile < ntiles && ntile * 16 + srow < n_nodes)
            zn = *(const float4*)(z + (size_t)(ntile * 16 + srow) * 64 + scol);

        if (tile < ntiles) {
            bf16x8 afrag[2];
#pragma unroll
            for (int kh = 0; kh < 2; ++kh)
                afrag[kh] = *(const bf16x8*)&zs[buf][lm][kh * 32 + q * 8];  // ds_read_b128

            f32x4 acc[4];
#pragma unroll
            for (int nt = 0; nt < 4; ++nt) acc[nt] = (f32x4){0.f, 0.f, 0.f, 0.f};
#pragma unroll
            for (int kh = 0; kh < 2; ++kh)
#pragma unroll
                for (int nt = 0; nt < 4; ++nt)
                    acc[nt] = __builtin_amdgcn_mfma_f32_16x16x32_bf16(
                        afrag[kh], bfrag[nt][kh], acc[nt], 0, 0, 0);

            // epilogue: C row=(q*4+r), col=lm -> UV[node][ncol], bias on U half
#pragma unroll
            for (int nt = 0; nt < 4; ++nt) {
                const int ncol = w * 64 + nt * 16 + lm;
#pragma unroll
                for (int r = 0; r < 4; ++r) {
                    const int node = node0 + q * 4 + r;
                    if (node < n_nodes)
                        UV[(size_t)node * 256 + ncol] = f2bf(acc[nt][r] + bias[nt]);
                }
            }
        }

        zv = zn;
        tile = ntile;
        // NOTE: no second barrier. Double-buffering makes the WAR safe: the
        // ds_write to buf B at iter i+2 happens after this wave passed the
        // barrier at iter i+1, which every wave reaches only after finishing
        // its compute (reads of B) at iter i.
    }
}

// ---------------- Kernel 2: per-edge gather + relu + dot (unchanged) ----------
__device__ inline float acc2(uint32_t u, uint32_t v, float w0, float w1, float s) {
    float ul = __builtin_bit_cast(float, u << 16);
    float uh = __builtin_bit_cast(float, u & 0xFFFF0000u);
    float vl = __builtin_bit_cast(float, v << 16);
    float vh = __builtin_bit_cast(float, v & 0xFFFF0000u);
    s = fmaf(fmaxf(ul + vl, 0.f), w0, s);
    s = fmaf(fmaxf(uh + vh, 0.f), w1, s);
    return s;
}

__global__ __launch_bounds__(256) void edge_kernel(
    const unsigned short* __restrict__ UV,
    const int* __restrict__ row, const int* __restrict__ col,
    const float* __restrict__ W2, const float* __restrict__ b2,
    float* __restrict__ out, int E)
{
    const int sub = threadIdx.x & 15;           // lane within 16-lane edge-group
    const float4 w2a = *(const float4*)&W2[sub * 8];
    const float4 w2b = *(const float4*)&W2[sub * 8 + 4];
    const float bb = b2[0];

    int g = blockIdx.x * 16 + (threadIdx.x >> 4);
    const int stride = gridDim.x * 16;

    for (; g < E; g += stride) {
        const int r = row[g];
        const int c = col[g];
        uint4 uu = *(const uint4*)(UV + (size_t)r * 256 + sub * 8);          // U half
        uint4 vv = *(const uint4*)(UV + (size_t)c * 256 + 128 + sub * 8);    // V half
        float s = 0.f;
        s = acc2(uu.x, vv.x, w2a.x, w2a.y, s);
        s = acc2(uu.y, vv.y, w2a.z, w2a.w, s);
        s = acc2(uu.z, vv.z, w2b.x, w2b.y, s);
        s = acc2(uu.w, vv.w, w2b.z, w2b.w, s);
        s += __shfl_xor(s, 1, 16);
        s += __shfl_xor(s, 2, 16);
        s += __shfl_xor(s, 4, 16);
        s += __shfl_xor(s, 8, 16);
        if (sub == 0) out[g] = s + bb;
    }
}

extern "C" void kernel_launch(void* const* d_in, const int* in_sizes, int n_in,
                              void* d_out, int out_size, void* d_ws, size_t ws_size,
                              hipStream_t stream) {
    const float* z   = (const float*)d_in[0];
    const int*   row = (const int*)d_in[1];
    const int*   col = (const int*)d_in[2];
    const float* W1  = (const float*)d_in[3];
    const float* b1  = (const float*)d_in[4];
    const float* W2  = (const float*)d_in[5];
    const float* b2  = (const float*)d_in[6];
    float* out = (float*)d_out;

    const int n_nodes = in_sizes[0] / 64;   // z is [N, 64]
    const int E = in_sizes[1];

    unsigned short* UV = (unsigned short*)d_ws;  // [n_nodes][256] bf16 = 51.2 MB

    node_precompute_mfma<<<2048, 256, 0, stream>>>(z, W1, b1, UV, n_nodes);

    edge_kernel<<<4096, 256, 0, stream>>>(UV, row, col, W2, b2, out, E);
}

// Round 2
// 317.581 us; speedup vs baseline: 1.0386x; 1.0386x over previous
//
#include <hip/hip_runtime.h>
#include <stdint.h>

// Decomposition (unchanged):
//   UV[n][j] = z[n] . Wcat[:,j] (+ b1[j] for j<128), stored bf16, j in 0..255
//   out[e] = b2 + sum_j W2[j] * relu(UV[row[e]][j] + UV[col[e]][128+j])
//
// R4 change (node kernel only; edge kernel byte-identical):
//   R3's occupancy/pipelining fix was a null -> the residual is either
//   (a) node time bound by its two INVARIANT parts: scattered 2-B UV stores
//       (4 cache lines per store inst) and the uncoalesced W1 fragment
//       prologue (64 scattered scalar loads/thread/block), or
//   (b) fixed harness dispatch overhead (~90-110 us of tiny reset dispatches
//       visible in the rocprof dispatch-id gaps), with node already ~20 us.
//   This round removes both (a) suspects: W1 staged to LDS via coalesced
//   float4 loads; UV epilogue staged to LDS then written as full-row uint4
//   (1024 B contiguous per wave). If total is unchanged again -> (b) holds,
//   edge kernel is at its random-gather ceiling, session is at roofline.

typedef __attribute__((ext_vector_type(8))) short bf16x8;
typedef __attribute__((ext_vector_type(4))) float f32x4;

__device__ inline unsigned short f2bf(float f) {
    uint32_t u = __builtin_bit_cast(uint32_t, f);
    uint32_t r = (u + 0x7FFFu + ((u >> 16) & 1u)) >> 16;  // RNE
    return (unsigned short)r;
}

// ---------------- Kernel 1: node precompute via MFMA --------------------------
// Block = 256 threads = 4 waves. Wave w owns output cols [w*64, w*64+64).
// B-fragments built from an LDS-staged bf16 copy of W1 (coalesced load).
// Per iteration: 16-node z tile in LDS (double-buffered) -> 8 MFMAs/wave ->
// C staged to LDS -> coalesced uint4 row stores.
__global__ __launch_bounds__(256) void node_precompute_mfma(
    const float* __restrict__ z, const float* __restrict__ W1,
    const float* __restrict__ b1, unsigned short* __restrict__ UV,
    int n_nodes)
{
    // LDS layout: zs [2][16][72] us (4608 B) | w1s [128][132] us (33792 B),
    // with uvs [16][264] us (8448 B) aliasing the w1s region after prologue.
    __shared__ __align__(16) char smem[4608 + 33792];
    typedef unsigned short us;
    us (*zs)[16][72] = (us(*)[16][72])smem;
    us (*w1s)[132]   = (us(*)[132])(smem + 4608);
    us (*uvs)[264]   = (us(*)[264])(smem + 4608);

    const int tid = threadIdx.x;
    const int w  = tid >> 6;    // wave 0..3
    const int l  = tid & 63;
    const int lm = l & 15;      // A-row / B-col / C-col sublane
    const int q  = l >> 4;      // quad 0..3

    // ---- one-time: stage W1 -> LDS bf16, coalesced float4 loads ----
    // 128 rows x 32 float4 = 4096 chunks / 256 threads = 16 per thread.
    for (int i = tid; i < 128 * 32; i += 256) {
        const int r = i >> 5;
        const int c = (i & 31) * 4;
        const float4 v = *(const float4*)(W1 + (size_t)r * 128 + c);
        us* p = &w1s[r][c];
        p[0] = f2bf(v.x); p[1] = f2bf(v.y); p[2] = f2bf(v.z); p[3] = f2bf(v.w);
    }
    __syncthreads();

    // ---- B-fragments + per-col bias from LDS ----
    bf16x8 bfrag[4][2];
    float  bias[4];
#pragma unroll
    for (int nt = 0; nt < 4; ++nt) {
        const int n    = w * 64 + nt * 16 + lm;            // output col 0..255
        const int rr   = (n < 128) ? n : n - 128;
        const int koff = (n < 128) ? 0 : 64;
#pragma unroll
        for (int kh = 0; kh < 2; ++kh) {
            const int k0 = koff + kh * 32 + q * 8;
            bf16x8 bb;
#pragma unroll
            for (int j = 0; j < 8; ++j) bb[j] = (short)w1s[rr][k0 + j];
            bfrag[nt][kh] = bb;
        }
        bias[nt] = (n < 128) ? b1[n] : 0.f;
    }
    // w1s is reused as uvs below. Safe: first uvs write happens after the
    // first staging barrier, which all threads reach only after finishing
    // their bfrag reads here (program order + barrier).

    const int ntiles = (n_nodes + 15) >> 4;
    const int iters = (ntiles + gridDim.x - 1) / gridDim.x;  // uniform for barriers
    int tile = blockIdx.x;

    const int srow = tid >> 4;        // staging: thread -> (row, 4-float chunk)
    const int scol = (tid & 15) * 4;

    // prefetch first tile into registers
    float4 zv = make_float4(0.f, 0.f, 0.f, 0.f);
    if (tile < ntiles && tile * 16 + srow < n_nodes)
        zv = *(const float4*)(z + (size_t)(tile * 16 + srow) * 64 + scol);

    for (int it = 0; it < iters; ++it) {
        const int buf = it & 1;
        const int node0 = tile * 16;

        if (tile < ntiles) {
            us* p = &zs[buf][srow][scol];   // waits vmcnt for zv
            p[0] = f2bf(zv.x); p[1] = f2bf(zv.y); p[2] = f2bf(zv.z); p[3] = f2bf(zv.w);
        }
        __syncthreads();   // (A) zs[buf] staged; also fences prior uvs reads

        // issue next tile's global load BEFORE compute
        const int ntile = tile + gridDim.x;
        float4 zn = make_float4(0.f, 0.f, 0.f, 0.f);
        if (it + 1 < iters && ntile < ntiles && ntile * 16 + srow < n_nodes)
            zn = *(const float4*)(z + (size_t)(ntile * 16 + srow) * 64 + scol);

        if (tile < ntiles) {
            bf16x8 afrag[2];
#pragma unroll
            for (int kh = 0; kh < 2; ++kh)
                afrag[kh] = *(const bf16x8*)&zs[buf][lm][kh * 32 + q * 8];  // ds_read_b128

            f32x4 acc[4];
#pragma unroll
            for (int nt = 0; nt < 4; ++nt) acc[nt] = (f32x4){0.f, 0.f, 0.f, 0.f};
#pragma unroll
            for (int kh = 0; kh < 2; ++kh)
#pragma unroll
                for (int nt = 0; nt < 4; ++nt)
                    acc[nt] = __builtin_amdgcn_mfma_f32_16x16x32_bf16(
                        afrag[kh], bfrag[nt][kh], acc[nt], 0, 0, 0);

            // stage C to LDS: row = q*4+r (node within tile), col = output col
#pragma unroll
            for (int nt = 0; nt < 4; ++nt) {
                const int ncol = w * 64 + nt * 16 + lm;
#pragma unroll
                for (int r = 0; r < 4; ++r)
                    uvs[q * 4 + r][ncol] = f2bf(acc[nt][r] + bias[nt]);
            }
        }
        __syncthreads();   // (B) uvs staged

        if (tile < ntiles) {
            // coalesced UV store: 16 rows x 512 B; wave writes 1024 B contiguous
#pragma unroll
            for (int h = 0; h < 2; ++h) {
                const int idx = h * 256 + tid;
                const int r   = idx >> 5;          // node row in tile
                const int seg = idx & 31;          // 16-B segment in row
                const int node = node0 + r;
                if (node < n_nodes) {
                    const uint4 val = *(const uint4*)&uvs[r][seg * 8];
                    *(uint4*)(UV + (size_t)node * 256 + seg * 8) = val;
                }
            }
        }

        zv = zn;
        tile = ntile;
        // WAR notes: uvs reads (above) at iter i complete per-thread before
        // barrier (A) of iter i+1; uvs writes at i+1 come after it. zs[buf]
        // rewrite at i+2 is two barriers past its readers at i.
    }
}

// ---------------- Kernel 2: per-edge gather + relu + dot (unchanged) ----------
__device__ inline float acc2(uint32_t u, uint32_t v, float w0, float w1, float s) {
    float ul = __builtin_bit_cast(float, u << 16);
    float uh = __builtin_bit_cast(float, u & 0xFFFF0000u);
    float vl = __builtin_bit_cast(float, v << 16);
    float vh = __builtin_bit_cast(float, v & 0xFFFF0000u);
    s = fmaf(fmaxf(ul + vl, 0.f), w0, s);
    s = fmaf(fmaxf(uh + vh, 0.f), w1, s);
    return s;
}

__global__ __launch_bounds__(256) void edge_kernel(
    const unsigned short* __restrict__ UV,
    const int* __restrict__ row, const int* __restrict__ col,
    const float* __restrict__ W2, const float* __restrict__ b2,
    float* __restrict__ out, int E)
{
    const int sub = threadIdx.x & 15;           // lane within 16-lane edge-group
    const float4 w2a = *(const float4*)&W2[sub * 8];
    const float4 w2b = *(const float4*)&W2[sub * 8 + 4];
    const float bb = b2[0];

    int g = blockIdx.x * 16 + (threadIdx.x >> 4);
    const int stride = gridDim.x * 16;

    for (; g < E; g += stride) {
        const int r = row[g];
        const int c = col[g];
        uint4 uu = *(const uint4*)(UV + (size_t)r * 256 + sub * 8);          // U half
        uint4 vv = *(const uint4*)(UV + (size_t)c * 256 + 128 + sub * 8);    // V half
        float s = 0.f;
        s = acc2(uu.x, vv.x, w2a.x, w2a.y, s);
        s = acc2(uu.y, vv.y, w2a.z, w2a.w, s);
        s = acc2(uu.z, vv.z, w2b.x, w2b.y, s);
        s = acc2(uu.w, vv.w, w2b.z, w2b.w, s);
        s += __shfl_xor(s, 1, 16);
        s += __shfl_xor(s, 2, 16);
        s += __shfl_xor(s, 4, 16);
        s += __shfl_xor(s, 8, 16);
        if (sub == 0) out[g] = s + bb;
    }
}

extern "C" void kernel_launch(void* const* d_in, const int* in_sizes, int n_in,
                              void* d_out, int out_size, void* d_ws, size_t ws_size,
                              hipStream_t stream) {
    const float* z   = (const float*)d_in[0];
    const int*   row = (const int*)d_in[1];
    const int*   col = (const int*)d_in[2];
    const float* W1  = (const float*)d_in[3];
    const float* b1  = (const float*)d_in[4];
    const float* W2  = (const float*)d_in[5];
    const float* b2  = (const float*)d_in[6];
    float* out = (float*)d_out;

    const int n_nodes = in_sizes[0] / 64;   // z is [N, 64]
    const int E = in_sizes[1];

    unsigned short* UV = (unsigned short*)d_ws;  // [n_nodes][256] bf16 = 51.2 MB

    // 38.4 KB LDS -> 4 blocks/CU; grid 1024 = fully resident, 7 tiles/block.
    node_precompute_mfma<<<1024, 256, 0, stream>>>(z, W1, b1, UV, n_nodes);

    edge_kernel<<<4096, 256, 0, stream>>>(UV, row, col, W2, b2, out, E);
}